// Round 1
// baseline (50.162 us; speedup 1.0000x reference)
//
#include <hip/hip_runtime.h>
#include <math.h>

// Problem constants (from reference setup_inputs):
//   x:  (256, 197, 384) f32   — row 0 is CLS, rows 1..196 are "nodes"
//   ea: (256, 196, 384) f32
//   out:(256, 50, 384)  f32   — [CLS, 49 selected nodes in ascending-score order]
#define NB      256
#define NNODES  196
#define NC      384
#define SEQ     197
#define START   147          // 196//4*3
#define KEEP    49           // 196 - 147
#define OUTROWS 50

__global__ __launch_bounds__(384)
void pooling_block_kernel(const float* __restrict__ x,
                          const float* __restrict__ ea,
                          float* __restrict__ out) {
    __shared__ float imp[NC];       // sigmoid(mean) per channel
    __shared__ float scores[NNODES];
    __shared__ int   sel[KEEP];     // sel[j] = node index with rank START+j

    const int b   = blockIdx.x;
    const int tid = threadIdx.x;    // 0..383

    // ---- Phase 1: per-channel mean over 196 rows, then sigmoid ----
    // Each thread owns one channel; reads are coalesced across the wave
    // (64 consecutive floats per wave per row).
    {
        const float* p = ea + (size_t)b * NNODES * NC + tid;
        double acc = 0.0;
        #pragma unroll 4
        for (int n = 0; n < NNODES; ++n)
            acc += (double)p[(size_t)n * NC];
        float m = (float)(acc * (1.0 / (double)NNODES));
        imp[tid] = 1.0f / (1.0f + expf(-m));
    }
    __syncthreads();

    // ---- Phase 2: node scores = dot(node_row, imp). Wave-per-node. ----
    const int wave = tid >> 6;      // 0..5
    const int lane = tid & 63;
    const float* nodes = x + ((size_t)b * SEQ + 1) * NC;  // skip CLS row

    for (int n = wave; n < NNODES; n += 6) {
        const float* row = nodes + (size_t)n * NC;
        double acc = 0.0;
        #pragma unroll
        for (int k = 0; k < 6; ++k) {
            int c = lane + 64 * k;               // coalesced across lanes
            acc += (double)row[c] * (double)imp[c];
        }
        // 64-lane butterfly reduction
        #pragma unroll
        for (int off = 32; off > 0; off >>= 1)
            acc += __shfl_xor(acc, off);
        if (lane == 0) scores[n] = (float)acc;
    }
    __syncthreads();

    // ---- Phase 3: stable ascending rank; keep ranks >= START ----
    if (tid < NNODES) {
        const float s = scores[tid];
        int rank = 0;
        for (int m = 0; m < NNODES; ++m) {
            const float sm = scores[m];
            rank += (sm < s) || (sm == s && m < tid);   // stable tie-break
        }
        if (rank >= START) sel[rank - START] = tid;
    }
    __syncthreads();

    // ---- Phase 4: write output rows (all coalesced, tid spans a row) ----
    float* orow = out + (size_t)b * OUTROWS * NC;
    // CLS row
    orow[tid] = x[(size_t)b * SEQ * NC + tid];
    // 49 selected node rows, in ascending-score order
    for (int j = 0; j < KEEP; ++j) {
        const int n = sel[j];
        orow[(size_t)(1 + j) * NC + tid] = nodes[(size_t)n * NC + tid];
    }
}

extern "C" void kernel_launch(void* const* d_in, const int* in_sizes, int n_in,
                              void* d_out, int out_size, void* d_ws, size_t ws_size,
                              hipStream_t stream) {
    const float* x   = (const float*)d_in[0];
    const float* ea  = (const float*)d_in[1];
    float* out       = (float*)d_out;

    hipLaunchKernelGGL(pooling_block_kernel,
                       dim3(NB), dim3(NC), 0, stream,
                       x, ea, out);
}

// Round 2
// 36.208 us; speedup vs baseline: 1.3854x; 1.3854x over previous
//
#include <hip/hip_runtime.h>
#include <math.h>

// Problem constants (from reference setup_inputs):
//   x:  (256, 197, 384) f32   — row 0 is CLS, rows 1..196 are "nodes"
//   ea: (256, 196, 384) f32
//   out:(256, 50, 384)  f32   — [CLS, 49 selected nodes in ascending-score order]
#define NB      256
#define NNODES  196
#define NC      384
#define SEQ     197
#define START   147          // 196//4*3
#define KEEP    49           // 196 - 147
#define OUTROWS 50

#define NT      960          // 15 waves
#define NWAVE   15
#define RG      10           // row-groups in phase 1
#define C4      96           // NC/4 float4 columns

__global__ __launch_bounds__(NT)
void pooling_block_kernel(const float* __restrict__ x,
                          const float* __restrict__ ea,
                          float* __restrict__ out) {
    __shared__ double partial[RG][NC];            // 30 KB
    __shared__ alignas(16) float imp[NC];         // sigmoid(mean) per channel
    __shared__ float scores[NNODES];
    __shared__ int   sel[KEEP];

    const int b   = blockIdx.x;
    const int tid = threadIdx.x;                  // 0..959

    // ---- Phase 1: per-channel mean over 196 rows (10-way row-split, float4) ----
    {
        const int rg = tid / C4;                  // 0..9
        const int c4 = tid % C4;                  // float4 column
        const float4* p = (const float4*)(ea + (size_t)b * NNODES * NC);
        double ax = 0.0, ay = 0.0, az = 0.0, aw = 0.0;
        for (int row = rg; row < NNODES; row += RG) {
            float4 v = p[(size_t)row * C4 + c4];  // coalesced: 96 consecutive float4
            ax += v.x; ay += v.y; az += v.z; aw += v.w;
        }
        partial[rg][4 * c4 + 0] = ax;
        partial[rg][4 * c4 + 1] = ay;
        partial[rg][4 * c4 + 2] = az;
        partial[rg][4 * c4 + 3] = aw;
    }
    __syncthreads();
    if (tid < NC) {
        double s = 0.0;
        #pragma unroll
        for (int rg = 0; rg < RG; ++rg) s += partial[rg][tid];
        float m = (float)(s * (1.0 / (double)NNODES));
        imp[tid] = 1.0f / (1.0f + expf(-m));
    }
    __syncthreads();

    // ---- Phase 2: node scores = dot(node_row, imp). Wave-per-node. ----
    const int wave = tid >> 6;                    // 0..14
    const int lane = tid & 63;
    const float* nodes = x + ((size_t)b * SEQ + 1) * NC;  // skip CLS row

    for (int n = wave; n < NNODES; n += NWAVE) {
        const float2* row2 = (const float2*)(nodes + (size_t)n * NC);
        const float2* imp2 = (const float2*)imp;
        double acc = 0.0;
        #pragma unroll
        for (int j = 0; j < 3; ++j) {
            int i = lane + 64 * j;                // coalesced float2 across lanes
            float2 v = row2[i];
            float2 w = imp2[i];
            acc += (double)v.x * (double)w.x + (double)v.y * (double)w.y;
        }
        #pragma unroll
        for (int off = 32; off > 0; off >>= 1)
            acc += __shfl_xor(acc, off);
        if (lane == 0) scores[n] = (float)acc;
    }
    __syncthreads();

    // ---- Phase 3: stable ascending rank; keep ranks >= START ----
    if (tid < NNODES) {
        const float s = scores[tid];
        int rank = 0;
        for (int m = 0; m < NNODES; ++m) {
            const float sm = scores[m];
            rank += (sm < s) || (sm == s && m < tid);   // stable tie-break
        }
        if (rank >= START) sel[rank - START] = tid;
    }
    __syncthreads();

    // ---- Phase 4: write output rows (float4, coalesced) ----
    {
        const int jg = tid / C4;                  // 0..9 (row group)
        const int c4 = tid % C4;
        const float4* nodes4 = (const float4*)nodes;
        const float4* cls4   = (const float4*)(x + (size_t)b * SEQ * NC);
        float4* out4         = (float4*)(out + (size_t)b * OUTROWS * NC);
        #pragma unroll
        for (int it = 0; it < 5; ++it) {
            int j = jg + RG * it;                 // 0..49
            const float4* src = (j == 0) ? cls4 : (nodes4 + (size_t)sel[j - 1] * C4);
            out4[(size_t)j * C4 + c4] = src[c4];
        }
    }
}

extern "C" void kernel_launch(void* const* d_in, const int* in_sizes, int n_in,
                              void* d_out, int out_size, void* d_ws, size_t ws_size,
                              hipStream_t stream) {
    const float* x   = (const float*)d_in[0];
    const float* ea  = (const float*)d_in[1];
    float* out       = (float*)d_out;

    hipLaunchKernelGGL(pooling_block_kernel,
                       dim3(NB), dim3(NT), 0, stream,
                       x, ea, out);
}